// Round 1
// baseline (326.427 us; speedup 1.0000x reference)
//
#include <hip/hip_runtime.h>

#define DEVI __device__ __forceinline__

typedef __attribute__((ext_vector_type(8))) short short8;
typedef __attribute__((ext_vector_type(4))) float f32x4;

DEVI unsigned short f2bf(float f) {
  unsigned int u = __float_as_uint(f);
  u += 0x7fffu + ((u >> 16) & 1u);
  return (unsigned short)(u >> 16);
}

DEVI void gload16(const void* g, void* l) {
  __builtin_amdgcn_global_load_lds((__attribute__((address_space(1))) void*)g,
                                   (__attribute__((address_space(3))) void*)l, 16, 0, 0);
}

// ---------------- weight transpose + bf16 convert ----------------
__global__ __launch_bounds__(256) void wprep(
    const float* __restrict__ Wq, const float* __restrict__ Wp,
    unsigned short* __restrict__ Wtq, unsigned short* __restrict__ Wtp) {
  int idx = blockIdx.x * 256 + threadIdx.x;
  int stride = gridDim.x * 256;
  for (int i = idx; i < 1536 * 512; i += stride) {
    int n = i >> 9, k = i & 511;
    Wtq[i] = f2bf(Wq[(size_t)k * 1536 + n]);
  }
  for (int i = idx; i < 512 * 512; i += stride) {
    int n = i >> 9, k = i & 511;
    Wtp[i] = f2bf(Wp[(size_t)k * 512 + n]);
  }
}

// ---------------- LayerNorm: one wave per 512-elem row ----------------
__global__ __launch_bounds__(256) void ln_kernel(
    const float* __restrict__ x, const float* __restrict__ gamma,
    const float* __restrict__ beta, unsigned short* __restrict__ xn) {
  int tid = threadIdx.x;
  int w = tid >> 6, l = tid & 63;
  size_t row = (size_t)blockIdx.x * 4 + w;
  const float* xr = x + row * 512 + l * 8;
  float4 v0 = *(const float4*)xr;
  float4 v1 = *(const float4*)(xr + 4);
  float s  = v0.x + v0.y + v0.z + v0.w + v1.x + v1.y + v1.z + v1.w;
  float ss = v0.x*v0.x + v0.y*v0.y + v0.z*v0.z + v0.w*v0.w
           + v1.x*v1.x + v1.y*v1.y + v1.z*v1.z + v1.w*v1.w;
  #pragma unroll
  for (int m = 1; m < 64; m <<= 1) {
    s  += __shfl_xor(s,  m);
    ss += __shfl_xor(ss, m);
  }
  float mean = s * (1.f / 512.f);
  float var  = ss * (1.f / 512.f) - mean * mean;
  float rstd = rsqrtf(var + 1e-5f);
  float4 g0 = *(const float4*)(gamma + l * 8);
  float4 g1 = *(const float4*)(gamma + l * 8 + 4);
  float4 b0 = *(const float4*)(beta + l * 8);
  float4 b1 = *(const float4*)(beta + l * 8 + 4);
  short8 ov;
  ov[0] = (short)f2bf((v0.x - mean) * rstd * g0.x + b0.x);
  ov[1] = (short)f2bf((v0.y - mean) * rstd * g0.y + b0.y);
  ov[2] = (short)f2bf((v0.z - mean) * rstd * g0.z + b0.z);
  ov[3] = (short)f2bf((v0.w - mean) * rstd * g0.w + b0.w);
  ov[4] = (short)f2bf((v1.x - mean) * rstd * g1.x + b1.x);
  ov[5] = (short)f2bf((v1.y - mean) * rstd * g1.y + b1.y);
  ov[6] = (short)f2bf((v1.z - mean) * rstd * g1.z + b1.z);
  ov[7] = (short)f2bf((v1.w - mean) * rstd * g1.w + b1.w);
  *(short8*)(xn + row * 512 + l * 8) = ov;
}

// ---------------- GEMM: C[M][N] = A[M][K] * Bt[N][K]^T  (m97 structure) ----------------
// EPI==0: bf16 out to Cbf.  EPI==1: f32 out = acc + bias[col] + resid[row*N+col].
template<int EPI>
__global__ __launch_bounds__(256, 2) void gemm_bt(
    const unsigned short* __restrict__ A, const unsigned short* __restrict__ Bt,
    unsigned short* __restrict__ Cbf, float* __restrict__ Cf,
    const float* __restrict__ bias, const float* __restrict__ resid,
    int M, int N, int K) {
  __shared__ unsigned short As[128 * 64];
  __shared__ unsigned short Bs[128 * 64];
  int tid = threadIdx.x;
  int w = tid >> 6, l = tid & 63;
  int bn = blockIdx.x, bm = blockIdx.y;
  int wr = w >> 1, wc = w & 1;
  int t8 = tid >> 3, c8 = (tid & 7) * 8;
  int lr = l & 15, lk4 = l >> 4;
  const unsigned short* Ab = A + (size_t)bm * 128 * K;
  const unsigned short* Bb = Bt + (size_t)bn * 128 * K;
  f32x4 zero = {0.f, 0.f, 0.f, 0.f};
  f32x4 acc[4][4];
  #pragma unroll
  for (int i = 0; i < 4; i++)
    #pragma unroll
    for (int j = 0; j < 4; j++) acc[i][j] = zero;

  for (int k0 = 0; k0 < K; k0 += 64) {
    #pragma unroll
    for (int i = 0; i < 4; i++) {
      gload16(Ab + (size_t)(i * 32 + t8) * K + k0 + c8, (char*)As + i * 4096 + w * 1024);
      gload16(Bb + (size_t)(i * 32 + t8) * K + k0 + c8, (char*)Bs + i * 4096 + w * 1024);
    }
    __syncthreads();
    #pragma unroll
    for (int kk = 0; kk < 2; kk++) {
      short8 a[4], b[4];
      #pragma unroll
      for (int i = 0; i < 4; i++)
        a[i] = *(const short8*)&As[(wr * 64 + i * 16 + lr) * 64 + kk * 32 + lk4 * 8];
      #pragma unroll
      for (int j = 0; j < 4; j++)
        b[j] = *(const short8*)&Bs[(wc * 64 + j * 16 + lr) * 64 + kk * 32 + lk4 * 8];
      #pragma unroll
      for (int i = 0; i < 4; i++)
        #pragma unroll
        for (int j = 0; j < 4; j++)
          acc[i][j] = __builtin_amdgcn_mfma_f32_16x16x32_bf16(a[i], b[j], acc[i][j], 0, 0, 0);
    }
    __syncthreads();
  }
  int rb = bm * 128 + wr * 64 + lk4 * 4;
  int cb = bn * 128 + wc * 64 + lr;
  if (EPI == 0) {
    #pragma unroll
    for (int i = 0; i < 4; i++)
      #pragma unroll
      for (int j = 0; j < 4; j++)
        #pragma unroll
        for (int r = 0; r < 4; r++)
          Cbf[(size_t)(rb + i * 16 + r) * N + (cb + j * 16)] = f2bf(acc[i][j][r]);
  } else {
    #pragma unroll
    for (int i = 0; i < 4; i++)
      #pragma unroll
      for (int j = 0; j < 4; j++)
        #pragma unroll
        for (int r = 0; r < 4; r++) {
          int row = rb + i * 16 + r, col = cb + j * 16;
          Cf[(size_t)row * N + col] = acc[i][j][r] + bias[col] + resid[(size_t)row * N + col];
        }
  }
}

// ---------------- fused masked attention: one block per (bv, h) ----------------
__global__ __launch_bounds__(256, 1) void attn_kernel(
    const unsigned short* __restrict__ qkv, unsigned short* __restrict__ aout,
    const int* __restrict__ obs_mask, const int* __restrict__ pad_mask) {
  const int LDQ = 72, LDP = 200;
  __shared__ unsigned short Qs[192 * 72];   // reused as Vt[64][200] after S
  __shared__ unsigned short Ks[192 * 72];
  __shared__ unsigned short Ps[192 * 200];
  __shared__ float obsb[192];
  __shared__ int padb[192];
  int h = blockIdx.x, bv = blockIdx.y;
  int tid = threadIdx.x, w = tid >> 6, l = tid & 63;
  int lr = l & 15, lk4 = l >> 4;
  int b = bv >> 5;
  for (int t = tid; t < 192; t += 256) {
    obsb[t] = (t == 0) ? 1.f : (float)obs_mask[bv * 191 + (t - 1)];
    padb[t] = (t == 0) ? 1 : pad_mask[b * 191 + (t - 1)];
  }
  const unsigned short* base = qkv + (size_t)bv * 192 * 1536 + h * 64;
  for (int s = tid; s < 192 * 8; s += 256) {
    int row = s >> 3, c = (s & 7) * 8;
    *(short8*)&Qs[row * LDQ + c] = *(const short8*)(base + (size_t)row * 1536 + c);
    *(short8*)&Ks[row * LDQ + c] = *(const short8*)(base + (size_t)row * 1536 + 512 + c);
  }
  __syncthreads();
  f32x4 zero = {0.f, 0.f, 0.f, 0.f};
  f32x4 sc[3][12];
  #pragma unroll
  for (int i = 0; i < 3; i++)
    #pragma unroll
    for (int j = 0; j < 12; j++) sc[i][j] = zero;
  #pragma unroll
  for (int kk = 0; kk < 2; kk++) {
    short8 a[3], bb[12];
    #pragma unroll
    for (int i = 0; i < 3; i++)
      a[i] = *(const short8*)&Qs[(w * 48 + i * 16 + lr) * LDQ + kk * 32 + lk4 * 8];
    #pragma unroll
    for (int j = 0; j < 12; j++)
      bb[j] = *(const short8*)&Ks[(j * 16 + lr) * LDQ + kk * 32 + lk4 * 8];
    #pragma unroll
    for (int i = 0; i < 3; i++)
      #pragma unroll
      for (int j = 0; j < 12; j++)
        sc[i][j] = __builtin_amdgcn_mfma_f32_16x16x32_bf16(a[i], bb[j], sc[i][j], 0, 0, 0);
  }
  __syncthreads();  // all waves done reading Qs
  // stage V transposed into Qs region: Vt[d(64)][k(192)] padded LDP
  unsigned short* Vt = Qs;
  for (int s = tid; s < 192 * 8; s += 256) {
    int row = s >> 3, d0 = (s & 7) * 8;
    short8 vv = *(const short8*)(base + (size_t)row * 1536 + 1024 + d0);
    #pragma unroll
    for (int e = 0; e < 8; e++)
      Vt[(d0 + e) * LDP + row] = (unsigned short)vv[e];
  }
  // softmax (fp32, in registers), write P (bf16) to LDS
  float colobs[12];
  int colpad[12];
  #pragma unroll
  for (int j = 0; j < 12; j++) {
    colobs[j] = obsb[j * 16 + lr];
    colpad[j] = padb[j * 16 + lr];
  }
  #pragma unroll
  for (int i = 0; i < 3; i++) {
    #pragma unroll
    for (int r = 0; r < 4; r++) {
      int row = w * 48 + i * 16 + lk4 * 4 + r;
      float ro = obsb[row];
      int rp = padb[row];
      float vals[12];
      float mx = -3.0e38f;
      #pragma unroll
      for (int j = 0; j < 12; j++) {
        float vv = sc[i][j][r] * 0.125f + ro + colobs[j]
                 + ((rp & colpad[j]) ? 0.f : -1e9f);
        vals[j] = vv;
        mx = fmaxf(mx, vv);
      }
      #pragma unroll
      for (int m = 1; m < 16; m <<= 1) mx = fmaxf(mx, __shfl_xor(mx, m));
      float sum = 0.f;
      #pragma unroll
      for (int j = 0; j < 12; j++) {
        float e = __expf(vals[j] - mx);
        vals[j] = e;
        sum += e;
      }
      #pragma unroll
      for (int m = 1; m < 16; m <<= 1) sum += __shfl_xor(sum, m);
      float inv = 1.f / sum;
      #pragma unroll
      for (int j = 0; j < 12; j++)
        Ps[row * LDP + j * 16 + lr] = f2bf(vals[j] * inv);
    }
  }
  __syncthreads();  // Vt staged by all threads, P visible
  // O = P @ V
  f32x4 o[3][4];
  #pragma unroll
  for (int i = 0; i < 3; i++)
    #pragma unroll
    for (int jd = 0; jd < 4; jd++) o[i][jd] = zero;
  #pragma unroll
  for (int kk = 0; kk < 6; kk++) {
    short8 a[3], bb[4];
    #pragma unroll
    for (int i = 0; i < 3; i++)
      a[i] = *(const short8*)&Ps[(w * 48 + i * 16 + lr) * LDP + kk * 32 + lk4 * 8];
    #pragma unroll
    for (int jd = 0; jd < 4; jd++)
      bb[jd] = *(const short8*)&Vt[(jd * 16 + lr) * LDP + kk * 32 + lk4 * 8];
    #pragma unroll
    for (int i = 0; i < 3; i++)
      #pragma unroll
      for (int jd = 0; jd < 4; jd++)
        o[i][jd] = __builtin_amdgcn_mfma_f32_16x16x32_bf16(a[i], bb[jd], o[i][jd], 0, 0, 0);
  }
  unsigned short* ob = aout + (size_t)bv * 192 * 512 + h * 64;
  #pragma unroll
  for (int i = 0; i < 3; i++)
    #pragma unroll
    for (int jd = 0; jd < 4; jd++)
      #pragma unroll
      for (int r = 0; r < 4; r++) {
        int t = w * 48 + i * 16 + lk4 * 4 + r;
        int d = jd * 16 + lr;
        ob[(size_t)t * 512 + d] = f2bf(o[i][jd][r]);
      }
}

extern "C" void kernel_launch(void* const* d_in, const int* in_sizes, int n_in,
                              void* d_out, int out_size, void* d_ws, size_t ws_size,
                              hipStream_t stream) {
  const float* x     = (const float*)d_in[0];
  const int*   obs   = (const int*)d_in[1];
  const int*   pad   = (const int*)d_in[2];
  const float* gamma = (const float*)d_in[3];
  const float* beta  = (const float*)d_in[4];
  const float* Wq    = (const float*)d_in[5];
  const float* Wp    = (const float*)d_in[6];
  const float* bp    = (const float*)d_in[7];
  float* out = (float*)d_out;
  char* ws = (char*)d_ws;

  const size_t M = 49152;  // BV * T1 = 256 * 192
  // workspace layout (total ~194 MB):
  unsigned short* xn  = (unsigned short*)ws;                             // M*512 bf16 (later reused as attn out)
  unsigned short* qkv = (unsigned short*)(ws + M * 512 * 2);             // M*1536 bf16
  unsigned short* Wtq = (unsigned short*)(ws + M * 512 * 2 + M * 1536 * 2);
  unsigned short* Wtp = Wtq + 1536 * 512;

  wprep<<<dim3(512), dim3(256), 0, stream>>>(Wq, Wp, Wtq, Wtp);
  ln_kernel<<<dim3(12288), dim3(256), 0, stream>>>(x, gamma, beta, xn);
  gemm_bt<0><<<dim3(12, 384), dim3(256), 0, stream>>>(
      xn, Wtq, qkv, nullptr, nullptr, nullptr, 49152, 1536, 512);
  attn_kernel<<<dim3(8, 256), dim3(256), 0, stream>>>(qkv, xn, obs, pad);
  gemm_bt<1><<<dim3(4, 384), dim3(256), 0, stream>>>(
      xn, Wtp, nullptr, out, bp, x, 49152, 512, 512);
}

// Round 2
// 284.214 us; speedup vs baseline: 1.1485x; 1.1485x over previous
//
#include <hip/hip_runtime.h>

#define DEVI __device__ __forceinline__

typedef __attribute__((ext_vector_type(8))) short short8;
typedef __attribute__((ext_vector_type(4))) float f32x4;

DEVI unsigned short f2bf(float f) {
  unsigned int u = __float_as_uint(f);
  u += 0x7fffu + ((u >> 16) & 1u);
  return (unsigned short)(u >> 16);
}

DEVI void gload16(const void* g, void* l) {
  __builtin_amdgcn_global_load_lds((__attribute__((address_space(1))) void*)g,
                                   (__attribute__((address_space(3))) void*)l, 16, 0, 0);
}

// ---------------- weight transpose + bf16 convert ----------------
__global__ __launch_bounds__(256) void wprep(
    const float* __restrict__ Wq, const float* __restrict__ Wp,
    unsigned short* __restrict__ Wtq, unsigned short* __restrict__ Wtp) {
  int idx = blockIdx.x * 256 + threadIdx.x;
  int stride = gridDim.x * 256;
  for (int i = idx; i < 1536 * 512; i += stride) {
    int n = i >> 9, k = i & 511;
    Wtq[i] = f2bf(Wq[(size_t)k * 1536 + n]);
  }
  for (int i = idx; i < 512 * 512; i += stride) {
    int n = i >> 9, k = i & 511;
    Wtp[i] = f2bf(Wp[(size_t)k * 512 + n]);
  }
}

// ---------------- LayerNorm: one wave per 512-elem row ----------------
__global__ __launch_bounds__(256) void ln_kernel(
    const float* __restrict__ x, const float* __restrict__ gamma,
    const float* __restrict__ beta, unsigned short* __restrict__ xn) {
  int tid = threadIdx.x;
  int w = tid >> 6, l = tid & 63;
  size_t row = (size_t)blockIdx.x * 4 + w;
  const float* xr = x + row * 512 + l * 8;
  float4 v0 = *(const float4*)xr;
  float4 v1 = *(const float4*)(xr + 4);
  float s  = v0.x + v0.y + v0.z + v0.w + v1.x + v1.y + v1.z + v1.w;
  float ss = v0.x*v0.x + v0.y*v0.y + v0.z*v0.z + v0.w*v0.w
           + v1.x*v1.x + v1.y*v1.y + v1.z*v1.z + v1.w*v1.w;
  #pragma unroll
  for (int m = 1; m < 64; m <<= 1) {
    s  += __shfl_xor(s,  m);
    ss += __shfl_xor(ss, m);
  }
  float mean = s * (1.f / 512.f);
  float var  = ss * (1.f / 512.f) - mean * mean;
  float rstd = rsqrtf(var + 1e-5f);
  float4 g0 = *(const float4*)(gamma + l * 8);
  float4 g1 = *(const float4*)(gamma + l * 8 + 4);
  float4 b0 = *(const float4*)(beta + l * 8);
  float4 b1 = *(const float4*)(beta + l * 8 + 4);
  short8 ov;
  ov[0] = (short)f2bf((v0.x - mean) * rstd * g0.x + b0.x);
  ov[1] = (short)f2bf((v0.y - mean) * rstd * g0.y + b0.y);
  ov[2] = (short)f2bf((v0.z - mean) * rstd * g0.z + b0.z);
  ov[3] = (short)f2bf((v0.w - mean) * rstd * g0.w + b0.w);
  ov[4] = (short)f2bf((v1.x - mean) * rstd * g1.x + b1.x);
  ov[5] = (short)f2bf((v1.y - mean) * rstd * g1.y + b1.y);
  ov[6] = (short)f2bf((v1.z - mean) * rstd * g1.z + b1.z);
  ov[7] = (short)f2bf((v1.w - mean) * rstd * g1.w + b1.w);
  *(short8*)(xn + row * 512 + l * 8) = ov;
}

// ---------------- GEMM: C[M][N] = A[M][K] * Bt[N][K]^T  (m97 structure) ----------------
template<int EPI>
__global__ __launch_bounds__(256, 2) void gemm_bt(
    const unsigned short* __restrict__ A, const unsigned short* __restrict__ Bt,
    unsigned short* __restrict__ Cbf, float* __restrict__ Cf,
    const float* __restrict__ bias, const float* __restrict__ resid,
    int M, int N, int K) {
  __shared__ unsigned short As[128 * 64];
  __shared__ unsigned short Bs[128 * 64];
  int tid = threadIdx.x;
  int w = tid >> 6, l = tid & 63;
  int bn = blockIdx.x, bm = blockIdx.y;
  int wr = w >> 1, wc = w & 1;
  int t8 = tid >> 3, c8 = (tid & 7) * 8;
  int lr = l & 15, lk4 = l >> 4;
  const unsigned short* Ab = A + (size_t)bm * 128 * K;
  const unsigned short* Bb = Bt + (size_t)bn * 128 * K;
  f32x4 zero = {0.f, 0.f, 0.f, 0.f};
  f32x4 acc[4][4];
  #pragma unroll
  for (int i = 0; i < 4; i++)
    #pragma unroll
    for (int j = 0; j < 4; j++) acc[i][j] = zero;

  for (int k0 = 0; k0 < K; k0 += 64) {
    #pragma unroll
    for (int i = 0; i < 4; i++) {
      gload16(Ab + (size_t)(i * 32 + t8) * K + k0 + c8, (char*)As + i * 4096 + w * 1024);
      gload16(Bb + (size_t)(i * 32 + t8) * K + k0 + c8, (char*)Bs + i * 4096 + w * 1024);
    }
    __syncthreads();
    #pragma unroll
    for (int kk = 0; kk < 2; kk++) {
      short8 a[4], b[4];
      #pragma unroll
      for (int i = 0; i < 4; i++)
        a[i] = *(const short8*)&As[(wr * 64 + i * 16 + lr) * 64 + kk * 32 + lk4 * 8];
      #pragma unroll
      for (int j = 0; j < 4; j++)
        b[j] = *(const short8*)&Bs[(wc * 64 + j * 16 + lr) * 64 + kk * 32 + lk4 * 8];
      #pragma unroll
      for (int i = 0; i < 4; i++)
        #pragma unroll
        for (int j = 0; j < 4; j++)
          acc[i][j] = __builtin_amdgcn_mfma_f32_16x16x32_bf16(a[i], b[j], acc[i][j], 0, 0, 0);
    }
    __syncthreads();
  }
  int rb = bm * 128 + wr * 64 + lk4 * 4;
  int cb = bn * 128 + wc * 64 + lr;
  if (EPI == 0) {
    #pragma unroll
    for (int i = 0; i < 4; i++)
      #pragma unroll
      for (int j = 0; j < 4; j++)
        #pragma unroll
        for (int r = 0; r < 4; r++)
          Cbf[(size_t)(rb + i * 16 + r) * N + (cb + j * 16)] = f2bf(acc[i][j][r]);
  } else {
    #pragma unroll
    for (int i = 0; i < 4; i++)
      #pragma unroll
      for (int j = 0; j < 4; j++)
        #pragma unroll
        for (int r = 0; r < 4; r++) {
          int row = rb + i * 16 + r, col = cb + j * 16;
          Cf[(size_t)row * N + col] = acc[i][j][r] + bias[col] + resid[(size_t)row * N + col];
        }
  }
}

// ---------------- fused masked attention: one block per (bv, h) ----------------
// LDS union (67072 B total -> 2 blocks/CU):
//   phase A: Qs[192][72] @0 (27648), Ks[192][72] @27648 (27648)
//   phase B: Vt[64][200] @0 swizzled (25600), Pw[4][48][104] @25600 (39936)
//   masks   @65536 (1536)
__global__ __launch_bounds__(256, 2) void attn_kernel(
    const unsigned short* __restrict__ qkv, unsigned short* __restrict__ aout,
    const int* __restrict__ obs_mask, const int* __restrict__ pad_mask) {
  const int LDQ = 72, LDV = 200, LDP = 104;
  __shared__ char smem[67072];
  unsigned short* Qs = (unsigned short*)smem;
  unsigned short* Ks = (unsigned short*)(smem + 27648);
  unsigned short* Vt = (unsigned short*)smem;
  unsigned short* Pw = (unsigned short*)(smem + 25600);
  float* obsb = (float*)(smem + 65536);
  int*   padb = (int*)(smem + 66304);

  int h = blockIdx.x, bv = blockIdx.y;
  int tid = threadIdx.x, w = tid >> 6, l = tid & 63;
  int lr = l & 15, lk4 = l >> 4;
  int b = bv >> 5;
  for (int t = tid; t < 192; t += 256) {
    obsb[t] = (t == 0) ? 1.f : (float)obs_mask[bv * 191 + (t - 1)];
    padb[t] = (t == 0) ? 1 : pad_mask[b * 191 + (t - 1)];
  }
  const unsigned short* base = qkv + (size_t)bv * 192 * 1536 + h * 64;
  for (int s = tid; s < 192 * 8; s += 256) {
    int row = s >> 3, c = (s & 7) * 8;
    *(short8*)&Qs[row * LDQ + c] = *(const short8*)(base + (size_t)row * 1536 + c);
    *(short8*)&Ks[row * LDQ + c] = *(const short8*)(base + (size_t)row * 1536 + 512 + c);
  }
  __syncthreads();
  f32x4 zero = {0.f, 0.f, 0.f, 0.f};
  f32x4 sc[3][12];
  #pragma unroll
  for (int i = 0; i < 3; i++)
    #pragma unroll
    for (int j = 0; j < 12; j++) sc[i][j] = zero;
  #pragma unroll
  for (int kk = 0; kk < 2; kk++) {
    short8 a[3], bb[12];
    #pragma unroll
    for (int i = 0; i < 3; i++)
      a[i] = *(const short8*)&Qs[(w * 48 + i * 16 + lr) * LDQ + kk * 32 + lk4 * 8];
    #pragma unroll
    for (int j = 0; j < 12; j++)
      bb[j] = *(const short8*)&Ks[(j * 16 + lr) * LDQ + kk * 32 + lk4 * 8];
    #pragma unroll
    for (int i = 0; i < 3; i++)
      #pragma unroll
      for (int j = 0; j < 12; j++)
        sc[i][j] = __builtin_amdgcn_mfma_f32_16x16x32_bf16(a[i], bb[j], sc[i][j], 0, 0, 0);
  }
  __syncthreads();  // Qs/Ks dead; phase B regions may be written now

  // stage V transposed + swizzled into Vt[d][k]: byte = (d*400 + k*2) ^ (((d>>3)&7)<<4)
  for (int s = tid; s < 192 * 8; s += 256) {
    int row = s >> 3, d0 = (s & 7) * 8;
    short8 vv = *(const short8*)(base + (size_t)row * 1536 + 1024 + d0);
    int slot = ((d0 >> 3) & 7) << 4;
    #pragma unroll
    for (int e = 0; e < 8; e++) {
      int byte = (((d0 + e) * (LDV * 2) + row * 2) ^ slot);
      *(unsigned short*)((char*)Vt + byte) = (unsigned short)vv[e];
    }
  }
  // softmax fully in registers; result written back into sc
  float colobs[12];
  int colpad[12];
  #pragma unroll
  for (int j = 0; j < 12; j++) {
    colobs[j] = obsb[j * 16 + lr];
    colpad[j] = padb[j * 16 + lr];
  }
  #pragma unroll
  for (int i = 0; i < 3; i++) {
    #pragma unroll
    for (int r = 0; r < 4; r++) {
      int row = w * 48 + i * 16 + lk4 * 4 + r;
      float ro = obsb[row];
      int rp = padb[row];
      float vals[12];
      float mx = -3.0e38f;
      #pragma unroll
      for (int j = 0; j < 12; j++) {
        float vv = sc[i][j][r] * 0.125f + ro + colobs[j]
                 + ((rp & colpad[j]) ? 0.f : -1e9f);
        vals[j] = vv;
        mx = fmaxf(mx, vv);
      }
      #pragma unroll
      for (int m = 1; m < 16; m <<= 1) mx = fmaxf(mx, __shfl_xor(mx, m));
      float sum = 0.f;
      #pragma unroll
      for (int j = 0; j < 12; j++) {
        float e = __expf(vals[j] - mx);
        vals[j] = e;
        sum += e;
      }
      #pragma unroll
      for (int m = 1; m < 16; m <<= 1) sum += __shfl_xor(sum, m);
      float inv = 1.f / sum;
      #pragma unroll
      for (int j = 0; j < 12; j++) sc[i][j][r] = vals[j] * inv;
    }
  }
  __syncthreads();  // Vt staged & visible to all waves

  // O = P @ V in two k-chunks of 96, P transposed through per-wave LDS
  unsigned short* Pme = Pw + w * 48 * LDP;
  f32x4 o[3][4];
  #pragma unroll
  for (int i = 0; i < 3; i++)
    #pragma unroll
    for (int jd = 0; jd < 4; jd++) o[i][jd] = zero;
  #pragma unroll
  for (int kc = 0; kc < 2; kc++) {
    #pragma unroll
    for (int i = 0; i < 3; i++)
      #pragma unroll
      for (int r = 0; r < 4; r++) {
        int row = i * 16 + lk4 * 4 + r;
        #pragma unroll
        for (int jj = 0; jj < 6; jj++)
          Pme[row * LDP + jj * 16 + lr] = f2bf(sc[i][kc * 6 + jj][r]);
      }
    asm volatile("s_waitcnt lgkmcnt(0)" ::: "memory");
    __builtin_amdgcn_sched_barrier(0);
    #pragma unroll
    for (int kk = 0; kk < 3; kk++) {
      short8 a[3], bb[4];
      #pragma unroll
      for (int i = 0; i < 3; i++)
        a[i] = *(const short8*)&Pme[(i * 16 + lr) * LDP + kk * 32 + lk4 * 8];
      #pragma unroll
      for (int jd = 0; jd < 4; jd++) {
        int d = jd * 16 + lr;
        int byte = ((d * (LDV * 2) + (kc * 96 + kk * 32 + lk4 * 8) * 2) ^ (((d >> 3) & 7) << 4));
        bb[jd] = *(const short8*)((const char*)Vt + byte);
      }
      #pragma unroll
      for (int i = 0; i < 3; i++)
        #pragma unroll
        for (int jd = 0; jd < 4; jd++)
          o[i][jd] = __builtin_amdgcn_mfma_f32_16x16x32_bf16(a[i], bb[jd], o[i][jd], 0, 0, 0);
    }
  }
  unsigned short* ob = aout + (size_t)bv * 192 * 512 + h * 64;
  #pragma unroll
  for (int i = 0; i < 3; i++)
    #pragma unroll
    for (int jd = 0; jd < 4; jd++)
      #pragma unroll
      for (int r = 0; r < 4; r++) {
        int t = w * 48 + i * 16 + lk4 * 4 + r;
        int d = jd * 16 + lr;
        ob[(size_t)t * 512 + d] = f2bf(o[i][jd][r]);
      }
}

extern "C" void kernel_launch(void* const* d_in, const int* in_sizes, int n_in,
                              void* d_out, int out_size, void* d_ws, size_t ws_size,
                              hipStream_t stream) {
  const float* x     = (const float*)d_in[0];
  const int*   obs   = (const int*)d_in[1];
  const int*   pad   = (const int*)d_in[2];
  const float* gamma = (const float*)d_in[3];
  const float* beta  = (const float*)d_in[4];
  const float* Wq    = (const float*)d_in[5];
  const float* Wp    = (const float*)d_in[6];
  const float* bp    = (const float*)d_in[7];
  float* out = (float*)d_out;
  char* ws = (char*)d_ws;

  const size_t M = 49152;  // BV * T1 = 256 * 192
  unsigned short* xn  = (unsigned short*)ws;                             // M*512 bf16 (reused as attn out)
  unsigned short* qkv = (unsigned short*)(ws + M * 512 * 2);             // M*1536 bf16
  unsigned short* Wtq = (unsigned short*)(ws + M * 512 * 2 + M * 1536 * 2);
  unsigned short* Wtp = Wtq + 1536 * 512;

  wprep<<<dim3(512), dim3(256), 0, stream>>>(Wq, Wp, Wtq, Wtp);
  ln_kernel<<<dim3(12288), dim3(256), 0, stream>>>(x, gamma, beta, xn);
  gemm_bt<0><<<dim3(12, 384), dim3(256), 0, stream>>>(
      xn, Wtq, qkv, nullptr, nullptr, nullptr, 49152, 1536, 512);
  attn_kernel<<<dim3(8, 256), dim3(256), 0, stream>>>(qkv, xn, obs, pad);
  gemm_bt<1><<<dim3(4, 384), dim3(256), 0, stream>>>(
      xn, Wtp, nullptr, out, bp, x, 49152, 512, 512);
}

// Round 3
// 260.123 us; speedup vs baseline: 1.2549x; 1.0926x over previous
//
#include <hip/hip_runtime.h>

#define DEVI __device__ __forceinline__

typedef __attribute__((ext_vector_type(8))) short short8;
typedef __attribute__((ext_vector_type(4))) float f32x4;

DEVI unsigned short f2bf(float f) {
  unsigned int u = __float_as_uint(f);
  u += 0x7fffu + ((u >> 16) & 1u);
  return (unsigned short)(u >> 16);
}

DEVI void gload16(const void* g, void* l) {
  __builtin_amdgcn_global_load_lds((__attribute__((address_space(1))) void*)g,
                                   (__attribute__((address_space(3))) void*)l, 16, 0, 0);
}

// ---------------- weight transpose + bf16 convert ----------------
__global__ __launch_bounds__(256) void wprep(
    const float* __restrict__ Wq, const float* __restrict__ Wp,
    unsigned short* __restrict__ Wtq, unsigned short* __restrict__ Wtp) {
  int idx = blockIdx.x * 256 + threadIdx.x;
  int stride = gridDim.x * 256;
  for (int i = idx; i < 1536 * 512; i += stride) {
    int n = i >> 9, k = i & 511;
    Wtq[i] = f2bf(Wq[(size_t)k * 1536 + n]);
  }
  for (int i = idx; i < 512 * 512; i += stride) {
    int n = i >> 9, k = i & 511;
    Wtp[i] = f2bf(Wp[(size_t)k * 512 + n]);
  }
}

// ---------------- LayerNorm: one wave per 512-elem row ----------------
__global__ __launch_bounds__(256) void ln_kernel(
    const float* __restrict__ x, const float* __restrict__ gamma,
    const float* __restrict__ beta, unsigned short* __restrict__ xn) {
  int tid = threadIdx.x;
  int w = tid >> 6, l = tid & 63;
  size_t row = (size_t)blockIdx.x * 4 + w;
  const float* xr = x + row * 512 + l * 8;
  float4 v0 = *(const float4*)xr;
  float4 v1 = *(const float4*)(xr + 4);
  float s  = v0.x + v0.y + v0.z + v0.w + v1.x + v1.y + v1.z + v1.w;
  float ss = v0.x*v0.x + v0.y*v0.y + v0.z*v0.z + v0.w*v0.w
           + v1.x*v1.x + v1.y*v1.y + v1.z*v1.z + v1.w*v1.w;
  #pragma unroll
  for (int m = 1; m < 64; m <<= 1) {
    s  += __shfl_xor(s,  m);
    ss += __shfl_xor(ss, m);
  }
  float mean = s * (1.f / 512.f);
  float var  = ss * (1.f / 512.f) - mean * mean;
  float rstd = rsqrtf(var + 1e-5f);
  float4 g0 = *(const float4*)(gamma + l * 8);
  float4 g1 = *(const float4*)(gamma + l * 8 + 4);
  float4 b0 = *(const float4*)(beta + l * 8);
  float4 b1 = *(const float4*)(beta + l * 8 + 4);
  short8 ov;
  ov[0] = (short)f2bf((v0.x - mean) * rstd * g0.x + b0.x);
  ov[1] = (short)f2bf((v0.y - mean) * rstd * g0.y + b0.y);
  ov[2] = (short)f2bf((v0.z - mean) * rstd * g0.z + b0.z);
  ov[3] = (short)f2bf((v0.w - mean) * rstd * g0.w + b0.w);
  ov[4] = (short)f2bf((v1.x - mean) * rstd * g1.x + b1.x);
  ov[5] = (short)f2bf((v1.y - mean) * rstd * g1.y + b1.y);
  ov[6] = (short)f2bf((v1.z - mean) * rstd * g1.z + b1.z);
  ov[7] = (short)f2bf((v1.w - mean) * rstd * g1.w + b1.w);
  *(short8*)(xn + row * 512 + l * 8) = ov;
}

// ---------------- GEMM: C[M][N] = A[M][K] * Bt[N][K]^T ----------------
// T2 swizzle: LDS dest linear (global_load_lds), global SOURCE column
// pre-swizzled by the same involution the reads apply:
//   slot(l) = (l&7), row-parity = (row&7); src col = ((l&7)^(row&7))*8
//   read byte = row*128 + ((kk*64 + lk4*16) ^ ((row&7)<<4))
// T1: chunked XCD remap (nwg % 8 == 0 for both call sites).
template<int EPI>
__global__ __launch_bounds__(256, 2) void gemm_bt(
    const unsigned short* __restrict__ A, const unsigned short* __restrict__ Bt,
    unsigned short* __restrict__ Cbf, float* __restrict__ Cf,
    const float* __restrict__ bias, const float* __restrict__ resid,
    int M, int N, int K, int nbx) {
  __shared__ unsigned short As[128 * 64];
  __shared__ unsigned short Bs[128 * 64];
  int tid = threadIdx.x;
  int w = tid >> 6, l = tid & 63;
  // chunked XCD swizzle: contiguous run of linear ids per XCD
  int nwg = nbx * gridDim.y;
  int lin = blockIdx.y * nbx + blockIdx.x;
  int cpx = nwg >> 3;
  int swz = (lin & 7) * cpx + (lin >> 3);
  int bn = swz % nbx, bm = swz / nbx;
  int wr = w >> 1, wc = w & 1;
  int t8 = tid >> 3;
  int c8s = (((tid & 7) ^ ((tid >> 3) & 7)) * 8);  // pre-swizzled source col
  int lr = l & 15, lk4 = l >> 4;
  const unsigned short* Ab = A + (size_t)bm * 128 * K;
  const unsigned short* Bb = Bt + (size_t)bn * 128 * K;
  f32x4 zero = {0.f, 0.f, 0.f, 0.f};
  f32x4 acc[4][4];
  #pragma unroll
  for (int i = 0; i < 4; i++)
    #pragma unroll
    for (int j = 0; j < 4; j++) acc[i][j] = zero;

  for (int k0 = 0; k0 < K; k0 += 64) {
    #pragma unroll
    for (int i = 0; i < 4; i++) {
      gload16(Ab + (size_t)(i * 32 + t8) * K + k0 + c8s, (char*)As + i * 4096 + w * 1024);
      gload16(Bb + (size_t)(i * 32 + t8) * K + k0 + c8s, (char*)Bs + i * 4096 + w * 1024);
    }
    __syncthreads();
    #pragma unroll
    for (int kk = 0; kk < 2; kk++) {
      short8 a[4], b[4];
      #pragma unroll
      for (int i = 0; i < 4; i++) {
        int ra = wr * 64 + i * 16 + lr;
        a[i] = *(const short8*)((const char*)As + ra * 128 +
                                (((kk * 64 + lk4 * 16)) ^ ((ra & 7) << 4)));
      }
      #pragma unroll
      for (int j = 0; j < 4; j++) {
        int rb = wc * 64 + j * 16 + lr;
        b[j] = *(const short8*)((const char*)Bs + rb * 128 +
                                (((kk * 64 + lk4 * 16)) ^ ((rb & 7) << 4)));
      }
      #pragma unroll
      for (int i = 0; i < 4; i++)
        #pragma unroll
        for (int j = 0; j < 4; j++)
          acc[i][j] = __builtin_amdgcn_mfma_f32_16x16x32_bf16(a[i], b[j], acc[i][j], 0, 0, 0);
    }
    __syncthreads();
  }
  int rb = bm * 128 + wr * 64 + lk4 * 4;
  int cb = bn * 128 + wc * 64 + lr;
  if (EPI == 0) {
    #pragma unroll
    for (int i = 0; i < 4; i++)
      #pragma unroll
      for (int j = 0; j < 4; j++)
        #pragma unroll
        for (int r = 0; r < 4; r++)
          Cbf[(size_t)(rb + i * 16 + r) * N + (cb + j * 16)] = f2bf(acc[i][j][r]);
  } else {
    #pragma unroll
    for (int i = 0; i < 4; i++)
      #pragma unroll
      for (int j = 0; j < 4; j++)
        #pragma unroll
        for (int r = 0; r < 4; r++) {
          int row = rb + i * 16 + r, col = cb + j * 16;
          Cf[(size_t)row * N + col] = acc[i][j][r] + bias[col] + resid[(size_t)row * N + col];
        }
  }
}

// ---------------- fused masked attention: one block per (bv, h) ----------------
// LDS union (67072 B total -> 2 blocks/CU):
//   phase A: Qs[192][72] @0 (27648), Ks[192][72] @27648 (27648)
//   phase B: Vt[64][200] @0 swizzled (25600), Pw[4][48][104] @25600 (39936)
//   masks   @65536 (1536)
__global__ __launch_bounds__(256, 2) void attn_kernel(
    const unsigned short* __restrict__ qkv, unsigned short* __restrict__ aout,
    const int* __restrict__ obs_mask, const int* __restrict__ pad_mask) {
  const int LDQ = 72, LDV = 200, LDP = 104;
  __shared__ char smem[67072];
  unsigned short* Qs = (unsigned short*)smem;
  unsigned short* Ks = (unsigned short*)(smem + 27648);
  unsigned short* Vt = (unsigned short*)smem;
  unsigned short* Pw = (unsigned short*)(smem + 25600);
  float* obsb = (float*)(smem + 65536);
  int*   padb = (int*)(smem + 66304);

  int h = blockIdx.x, bv = blockIdx.y;
  int tid = threadIdx.x, w = tid >> 6, l = tid & 63;
  int lr = l & 15, lk4 = l >> 4;
  int b = bv >> 5;
  for (int t = tid; t < 192; t += 256) {
    obsb[t] = (t == 0) ? 1.f : (float)obs_mask[bv * 191 + (t - 1)];
    padb[t] = (t == 0) ? 1 : pad_mask[b * 191 + (t - 1)];
  }
  const unsigned short* base = qkv + (size_t)bv * 192 * 1536 + h * 64;
  for (int s = tid; s < 192 * 8; s += 256) {
    int row = s >> 3, c = (s & 7) * 8;
    *(short8*)&Qs[row * LDQ + c] = *(const short8*)(base + (size_t)row * 1536 + c);
    *(short8*)&Ks[row * LDQ + c] = *(const short8*)(base + (size_t)row * 1536 + 512 + c);
  }
  __syncthreads();
  f32x4 zero = {0.f, 0.f, 0.f, 0.f};
  f32x4 sc[3][12];
  #pragma unroll
  for (int i = 0; i < 3; i++)
    #pragma unroll
    for (int j = 0; j < 12; j++) sc[i][j] = zero;
  #pragma unroll
  for (int kk = 0; kk < 2; kk++) {
    short8 a[3], bb[12];
    #pragma unroll
    for (int i = 0; i < 3; i++)
      a[i] = *(const short8*)&Qs[(w * 48 + i * 16 + lr) * LDQ + kk * 32 + lk4 * 8];
    #pragma unroll
    for (int j = 0; j < 12; j++)
      bb[j] = *(const short8*)&Ks[(j * 16 + lr) * LDQ + kk * 32 + lk4 * 8];
    #pragma unroll
    for (int i = 0; i < 3; i++)
      #pragma unroll
      for (int j = 0; j < 12; j++)
        sc[i][j] = __builtin_amdgcn_mfma_f32_16x16x32_bf16(a[i], bb[j], sc[i][j], 0, 0, 0);
  }
  __syncthreads();  // Qs/Ks dead; phase B regions may be written now

  // stage V transposed + swizzled into Vt[d][k]: byte = (d*400 + k*2) ^ (((d>>3)&7)<<4)
  for (int s = tid; s < 192 * 8; s += 256) {
    int row = s >> 3, d0 = (s & 7) * 8;
    short8 vv = *(const short8*)(base + (size_t)row * 1536 + 1024 + d0);
    int slot = ((d0 >> 3) & 7) << 4;
    #pragma unroll
    for (int e = 0; e < 8; e++) {
      int byte = (((d0 + e) * (LDV * 2) + row * 2) ^ slot);
      *(unsigned short*)((char*)Vt + byte) = (unsigned short)vv[e];
    }
  }
  // softmax fully in registers; result written back into sc
  float colobs[12];
  int colpad[12];
  #pragma unroll
  for (int j = 0; j < 12; j++) {
    colobs[j] = obsb[j * 16 + lr];
    colpad[j] = padb[j * 16 + lr];
  }
  #pragma unroll
  for (int i = 0; i < 3; i++) {
    #pragma unroll
    for (int r = 0; r < 4; r++) {
      int row = w * 48 + i * 16 + lk4 * 4 + r;
      float ro = obsb[row];
      int rp = padb[row];
      float vals[12];
      float mx = -3.0e38f;
      #pragma unroll
      for (int j = 0; j < 12; j++) {
        float vv = sc[i][j][r] * 0.125f + ro + colobs[j]
                 + ((rp & colpad[j]) ? 0.f : -1e9f);
        vals[j] = vv;
        mx = fmaxf(mx, vv);
      }
      #pragma unroll
      for (int m = 1; m < 16; m <<= 1) mx = fmaxf(mx, __shfl_xor(mx, m));
      float sum = 0.f;
      #pragma unroll
      for (int j = 0; j < 12; j++) {
        float e = __expf(vals[j] - mx);
        vals[j] = e;
        sum += e;
      }
      #pragma unroll
      for (int m = 1; m < 16; m <<= 1) sum += __shfl_xor(sum, m);
      float inv = 1.f / sum;
      #pragma unroll
      for (int j = 0; j < 12; j++) sc[i][j][r] = vals[j] * inv;
    }
  }
  __syncthreads();  // Vt staged & visible to all waves

  // O = P @ V in two k-chunks of 96, P transposed through per-wave LDS
  unsigned short* Pme = Pw + w * 48 * LDP;
  f32x4 o[3][4];
  #pragma unroll
  for (int i = 0; i < 3; i++)
    #pragma unroll
    for (int jd = 0; jd < 4; jd++) o[i][jd] = zero;
  #pragma unroll
  for (int kc = 0; kc < 2; kc++) {
    #pragma unroll
    for (int i = 0; i < 3; i++)
      #pragma unroll
      for (int r = 0; r < 4; r++) {
        int row = i * 16 + lk4 * 4 + r;
        #pragma unroll
        for (int jj = 0; jj < 6; jj++)
          Pme[row * LDP + jj * 16 + lr] = f2bf(sc[i][kc * 6 + jj][r]);
      }
    asm volatile("s_waitcnt lgkmcnt(0)" ::: "memory");
    __builtin_amdgcn_sched_barrier(0);
    #pragma unroll
    for (int kk = 0; kk < 3; kk++) {
      short8 a[3], bb[4];
      #pragma unroll
      for (int i = 0; i < 3; i++)
        a[i] = *(const short8*)&Pme[(i * 16 + lr) * LDP + kk * 32 + lk4 * 8];
      #pragma unroll
      for (int jd = 0; jd < 4; jd++) {
        int d = jd * 16 + lr;
        int byte = ((d * (LDV * 2) + (kc * 96 + kk * 32 + lk4 * 8) * 2) ^ (((d >> 3) & 7) << 4));
        bb[jd] = *(const short8*)((const char*)Vt + byte);
      }
      #pragma unroll
      for (int i = 0; i < 3; i++)
        #pragma unroll
        for (int jd = 0; jd < 4; jd++)
          o[i][jd] = __builtin_amdgcn_mfma_f32_16x16x32_bf16(a[i], bb[jd], o[i][jd], 0, 0, 0);
    }
  }
  unsigned short* ob = aout + (size_t)bv * 192 * 512 + h * 64;
  #pragma unroll
  for (int i = 0; i < 3; i++)
    #pragma unroll
    for (int jd = 0; jd < 4; jd++)
      #pragma unroll
      for (int r = 0; r < 4; r++) {
        int t = w * 48 + i * 16 + lk4 * 4 + r;
        int d = jd * 16 + lr;
        ob[(size_t)t * 512 + d] = f2bf(o[i][jd][r]);
      }
}

extern "C" void kernel_launch(void* const* d_in, const int* in_sizes, int n_in,
                              void* d_out, int out_size, void* d_ws, size_t ws_size,
                              hipStream_t stream) {
  const float* x     = (const float*)d_in[0];
  const int*   obs   = (const int*)d_in[1];
  const int*   pad   = (const int*)d_in[2];
  const float* gamma = (const float*)d_in[3];
  const float* beta  = (const float*)d_in[4];
  const float* Wq    = (const float*)d_in[5];
  const float* Wp    = (const float*)d_in[6];
  const float* bp    = (const float*)d_in[7];
  float* out = (float*)d_out;
  char* ws = (char*)d_ws;

  const size_t M = 49152;  // BV * T1 = 256 * 192
  unsigned short* xn  = (unsigned short*)ws;                             // M*512 bf16 (reused as attn out)
  unsigned short* qkv = (unsigned short*)(ws + M * 512 * 2);             // M*1536 bf16
  unsigned short* Wtq = (unsigned short*)(ws + M * 512 * 2 + M * 1536 * 2);
  unsigned short* Wtp = Wtq + 1536 * 512;

  wprep<<<dim3(512), dim3(256), 0, stream>>>(Wq, Wp, Wtq, Wtp);
  ln_kernel<<<dim3(12288), dim3(256), 0, stream>>>(x, gamma, beta, xn);
  gemm_bt<0><<<dim3(12, 384), dim3(256), 0, stream>>>(
      xn, Wtq, qkv, nullptr, nullptr, nullptr, 49152, 1536, 512, 12);
  attn_kernel<<<dim3(8, 256), dim3(256), 0, stream>>>(qkv, xn, obs, pad);
  gemm_bt<1><<<dim3(4, 384), dim3(256), 0, stream>>>(
      xn, Wtp, nullptr, out, bp, x, 49152, 512, 512, 4);
}

// Round 7
// 252.684 us; speedup vs baseline: 1.2918x; 1.0294x over previous
//
#include <hip/hip_runtime.h>

#define DEVI __device__ __forceinline__

typedef __attribute__((ext_vector_type(8))) short short8;
typedef __attribute__((ext_vector_type(4))) float f32x4;

DEVI unsigned short f2bf(float f) {
  unsigned int u = __float_as_uint(f);
  u += 0x7fffu + ((u >> 16) & 1u);
  return (unsigned short)(u >> 16);
}

DEVI void gload16(const void* g, void* l) {
  __builtin_amdgcn_global_load_lds((__attribute__((address_space(1))) void*)g,
                                   (__attribute__((address_space(3))) void*)l, 16, 0, 0);
}

// ---------------- weight transpose + bf16 convert ----------------
__global__ __launch_bounds__(256) void wprep(
    const float* __restrict__ Wq, const float* __restrict__ Wp,
    unsigned short* __restrict__ Wtq, unsigned short* __restrict__ Wtp) {
  int idx = blockIdx.x * 256 + threadIdx.x;
  int stride = gridDim.x * 256;
  for (int i = idx; i < 1536 * 512; i += stride) {
    int n = i >> 9, k = i & 511;
    Wtq[i] = f2bf(Wq[(size_t)k * 1536 + n]);
  }
  for (int i = idx; i < 512 * 512; i += stride) {
    int n = i >> 9, k = i & 511;
    Wtp[i] = f2bf(Wp[(size_t)k * 512 + n]);
  }
}

// ---------------- LayerNorm: one wave per 512-elem row ----------------
__global__ __launch_bounds__(256) void ln_kernel(
    const float* __restrict__ x, const float* __restrict__ gamma,
    const float* __restrict__ beta, unsigned short* __restrict__ xn) {
  int tid = threadIdx.x;
  int w = tid >> 6, l = tid & 63;
  size_t row = (size_t)blockIdx.x * 4 + w;
  const float* xr = x + row * 512 + l * 8;
  float4 v0 = *(const float4*)xr;
  float4 v1 = *(const float4*)(xr + 4);
  float s  = v0.x + v0.y + v0.z + v0.w + v1.x + v1.y + v1.z + v1.w;
  float ss = v0.x*v0.x + v0.y*v0.y + v0.z*v0.z + v0.w*v0.w
           + v1.x*v1.x + v1.y*v1.y + v1.z*v1.z + v1.w*v1.w;
  #pragma unroll
  for (int m = 1; m < 64; m <<= 1) {
    s  += __shfl_xor(s,  m);
    ss += __shfl_xor(ss, m);
  }
  float mean = s * (1.f / 512.f);
  float var  = ss * (1.f / 512.f) - mean * mean;
  float rstd = rsqrtf(var + 1e-5f);
  float4 g0 = *(const float4*)(gamma + l * 8);
  float4 g1 = *(const float4*)(gamma + l * 8 + 4);
  float4 b0 = *(const float4*)(beta + l * 8);
  float4 b1 = *(const float4*)(beta + l * 8 + 4);
  short8 ov;
  ov[0] = (short)f2bf((v0.x - mean) * rstd * g0.x + b0.x);
  ov[1] = (short)f2bf((v0.y - mean) * rstd * g0.y + b0.y);
  ov[2] = (short)f2bf((v0.z - mean) * rstd * g0.z + b0.z);
  ov[3] = (short)f2bf((v0.w - mean) * rstd * g0.w + b0.w);
  ov[4] = (short)f2bf((v1.x - mean) * rstd * g1.x + b1.x);
  ov[5] = (short)f2bf((v1.y - mean) * rstd * g1.y + b1.y);
  ov[6] = (short)f2bf((v1.z - mean) * rstd * g1.z + b1.z);
  ov[7] = (short)f2bf((v1.w - mean) * rstd * g1.w + b1.w);
  *(short8*)(xn + row * 512 + l * 8) = ov;
}

// ---------------- GEMM: C[M][N] = A[M][K] * Bt[N][K]^T (T2 swizzle + XCD remap) ----------------
template<int EPI>
__global__ __launch_bounds__(256, 2) void gemm_bt(
    const unsigned short* __restrict__ A, const unsigned short* __restrict__ Bt,
    unsigned short* __restrict__ Cbf, float* __restrict__ Cf,
    const float* __restrict__ bias, const float* __restrict__ resid,
    int M, int N, int K, int nbx) {
  __shared__ unsigned short As[128 * 64];
  __shared__ unsigned short Bs[128 * 64];
  int tid = threadIdx.x;
  int w = tid >> 6, l = tid & 63;
  int nwg = nbx * gridDim.y;
  int lin = blockIdx.y * nbx + blockIdx.x;
  int cpx = nwg >> 3;
  int swz = (lin & 7) * cpx + (lin >> 3);
  int bn = swz % nbx, bm = swz / nbx;
  int wr = w >> 1, wc = w & 1;
  int t8 = tid >> 3;
  int c8s = (((tid & 7) ^ ((tid >> 3) & 7)) * 8);
  int lr = l & 15, lk4 = l >> 4;
  const unsigned short* Ab = A + (size_t)bm * 128 * K;
  const unsigned short* Bb = Bt + (size_t)bn * 128 * K;
  f32x4 zero = {0.f, 0.f, 0.f, 0.f};
  f32x4 acc[4][4];
  #pragma unroll
  for (int i = 0; i < 4; i++)
    #pragma unroll
    for (int j = 0; j < 4; j++) acc[i][j] = zero;

  for (int k0 = 0; k0 < K; k0 += 64) {
    #pragma unroll
    for (int i = 0; i < 4; i++) {
      gload16(Ab + (size_t)(i * 32 + t8) * K + k0 + c8s, (char*)As + i * 4096 + w * 1024);
      gload16(Bb + (size_t)(i * 32 + t8) * K + k0 + c8s, (char*)Bs + i * 4096 + w * 1024);
    }
    __syncthreads();
    #pragma unroll
    for (int kk = 0; kk < 2; kk++) {
      short8 a[4], b[4];
      #pragma unroll
      for (int i = 0; i < 4; i++) {
        int ra = wr * 64 + i * 16 + lr;
        a[i] = *(const short8*)((const char*)As + ra * 128 +
                                (((kk * 64 + lk4 * 16)) ^ ((ra & 7) << 4)));
      }
      #pragma unroll
      for (int j = 0; j < 4; j++) {
        int rb = wc * 64 + j * 16 + lr;
        b[j] = *(const short8*)((const char*)Bs + rb * 128 +
                                (((kk * 64 + lk4 * 16)) ^ ((rb & 7) << 4)));
      }
      #pragma unroll
      for (int i = 0; i < 4; i++)
        #pragma unroll
        for (int j = 0; j < 4; j++)
          acc[i][j] = __builtin_amdgcn_mfma_f32_16x16x32_bf16(a[i], b[j], acc[i][j], 0, 0, 0);
    }
    __syncthreads();
  }
  int rb = bm * 128 + wr * 64 + lk4 * 4;
  int cb = bn * 128 + wc * 64 + lr;
  if (EPI == 0) {
    #pragma unroll
    for (int i = 0; i < 4; i++)
      #pragma unroll
      for (int j = 0; j < 4; j++)
        #pragma unroll
        for (int r = 0; r < 4; r++)
          Cbf[(size_t)(rb + i * 16 + r) * N + (cb + j * 16)] = f2bf(acc[i][j][r]);
  } else {
    #pragma unroll
    for (int i = 0; i < 4; i++)
      #pragma unroll
      for (int j = 0; j < 4; j++)
        #pragma unroll
        for (int r = 0; r < 4; r++) {
          int row = rb + i * 16 + r, col = cb + j * 16;
          Cf[(size_t)row * N + col] = acc[i][j][r] + bias[col] + resid[(size_t)row * N + col];
        }
  }
}

// ---------------- fused masked attention — BISECTION PROBE ----------------
// r3's bench-verified kernel with exactly two changes:
//  (a) K staged via global_load_lds + T2 swizzle into linear [192][128B] @0
//  (b) Q fragments loaded directly from global (identical values to r3's LDS path)
// Everything downstream (tables, V transpose+swizzle, softmax, Pw PV, store) is
// byte-identical to r3's passing kernel.
// LDS (67072 B -> 2 blocks/CU):
//   phase A: KsB @0 [192 rows][128 B] swizzled
//   phase B: Vt  @0 [64][200] elems, r3 swizzle; Pw @25600 per-wave 48x104 elems
//   obsb @65536, padb @66304
__global__ __launch_bounds__(256, 2) void attn_kernel(
    const unsigned short* __restrict__ qkv, unsigned short* __restrict__ aout,
    const int* __restrict__ obs_mask, const int* __restrict__ pad_mask) {
  const int LDV = 200, LDP = 104;
  __shared__ __align__(16) char smem[67072];
  char* KsB = smem;
  unsigned short* Vt = (unsigned short*)smem;      // aliases KsB after sync#2
  unsigned short* Pw = (unsigned short*)(smem + 25600);
  float* obsb = (float*)(smem + 65536);
  int*   padb = (int*)(smem + 66304);

  int h = blockIdx.x, bv = blockIdx.y;
  int tid = threadIdx.x, w = tid >> 6, l = tid & 63;
  int lr = l & 15, lk4 = l >> 4;
  int b = bv >> 5;
  // r3 table build (all threads)
  for (int t = tid; t < 192; t += 256) {
    obsb[t] = (t == 0) ? 1.f : (float)obs_mask[bv * 191 + (t - 1)];
    padb[t] = (t == 0) ? 1 : pad_mask[b * 191 + (t - 1)];
  }
  const unsigned short* base = qkv + (size_t)bv * 192 * 1536 + h * 64;

  // (a) stage K via gload16, source column pre-swizzled
  #pragma unroll
  for (int it = 0; it < 6; it++) {
    int s = it * 256 + tid;
    int row = s >> 3, slot = s & 7;
    gload16(base + (size_t)row * 1536 + 512 + (slot ^ (row & 7)) * 8,
            KsB + it * 4096 + w * 1024);
  }
  // (b) Q fragments direct from global (same values r3 read via Qs LDS)
  short8 qf[3][2];
  #pragma unroll
  for (int i = 0; i < 3; i++)
    #pragma unroll
    for (int kk = 0; kk < 2; kk++)
      qf[i][kk] = *(const short8*)(base + (size_t)(w * 48 + i * 16 + lr) * 1536 + kk * 32 + lk4 * 8);

  __syncthreads();
  f32x4 zero = {0.f, 0.f, 0.f, 0.f};
  f32x4 sc[3][12];
  #pragma unroll
  for (int i = 0; i < 3; i++)
    #pragma unroll
    for (int j = 0; j < 12; j++) sc[i][j] = zero;
  #pragma unroll
  for (int kk = 0; kk < 2; kk++) {
    short8 bb[12];
    #pragma unroll
    for (int j = 0; j < 12; j++) {
      int row = j * 16 + lr;
      bb[j] = *(const short8*)(KsB + row * 128 + ((kk * 64 + lk4 * 16) ^ ((row & 7) << 4)));
    }
    #pragma unroll
    for (int i = 0; i < 3; i++)
      #pragma unroll
      for (int j = 0; j < 12; j++)
        sc[i][j] = __builtin_amdgcn_mfma_f32_16x16x32_bf16(qf[i][kk], bb[j], sc[i][j], 0, 0, 0);
  }
  __syncthreads();  // all waves done reading KsB

  // ---- r3 verbatim: stage V transposed + swizzled into Vt ----
  for (int s = tid; s < 192 * 8; s += 256) {
    int row = s >> 3, d0 = (s & 7) * 8;
    short8 vv = *(const short8*)(base + (size_t)row * 1536 + 1024 + d0);
    int slot = ((d0 >> 3) & 7) << 4;
    #pragma unroll
    for (int e = 0; e < 8; e++) {
      int byte = (((d0 + e) * (LDV * 2) + row * 2) ^ slot);
      *(unsigned short*)((char*)Vt + byte) = (unsigned short)vv[e];
    }
  }
  // ---- r3 verbatim: softmax fully in registers ----
  float colobs[12];
  int colpad[12];
  #pragma unroll
  for (int j = 0; j < 12; j++) {
    colobs[j] = obsb[j * 16 + lr];
    colpad[j] = padb[j * 16 + lr];
  }
  #pragma unroll
  for (int i = 0; i < 3; i++) {
    #pragma unroll
    for (int r = 0; r < 4; r++) {
      int row = w * 48 + i * 16 + lk4 * 4 + r;
      float ro = obsb[row];
      int rp = padb[row];
      float vals[12];
      float mx = -3.0e38f;
      #pragma unroll
      for (int j = 0; j < 12; j++) {
        float vv = sc[i][j][r] * 0.125f + ro + colobs[j]
                 + ((rp & colpad[j]) ? 0.f : -1e9f);
        vals[j] = vv;
        mx = fmaxf(mx, vv);
      }
      #pragma unroll
      for (int m = 1; m < 16; m <<= 1) mx = fmaxf(mx, __shfl_xor(mx, m));
      float sum = 0.f;
      #pragma unroll
      for (int j = 0; j < 12; j++) {
        float e = __expf(vals[j] - mx);
        vals[j] = e;
        sum += e;
      }
      #pragma unroll
      for (int m = 1; m < 16; m <<= 1) sum += __shfl_xor(sum, m);
      float inv = 1.f / sum;
      #pragma unroll
      for (int j = 0; j < 12; j++) sc[i][j][r] = vals[j] * inv;
    }
  }
  __syncthreads();  // Vt staged & visible to all waves

  // ---- r3 verbatim: PV in two k-chunks of 96, P through per-wave LDS ----
  unsigned short* Pme = Pw + w * 48 * LDP;
  f32x4 o[3][4];
  #pragma unroll
  for (int i = 0; i < 3; i++)
    #pragma unroll
    for (int jd = 0; jd < 4; jd++) o[i][jd] = zero;
  #pragma unroll
  for (int kc = 0; kc < 2; kc++) {
    #pragma unroll
    for (int i = 0; i < 3; i++)
      #pragma unroll
      for (int r = 0; r < 4; r++) {
        int row = i * 16 + lk4 * 4 + r;
        #pragma unroll
        for (int jj = 0; jj < 6; jj++)
          Pme[row * LDP + jj * 16 + lr] = f2bf(sc[i][kc * 6 + jj][r]);
      }
    asm volatile("s_waitcnt lgkmcnt(0)" ::: "memory");
    __builtin_amdgcn_sched_barrier(0);
    #pragma unroll
    for (int kk = 0; kk < 3; kk++) {
      short8 a[3], bb[4];
      #pragma unroll
      for (int i = 0; i < 3; i++)
        a[i] = *(const short8*)&Pme[(i * 16 + lr) * LDP + kk * 32 + lk4 * 8];
      #pragma unroll
      for (int jd = 0; jd < 4; jd++) {
        int d = jd * 16 + lr;
        int byte = ((d * (LDV * 2) + (kc * 96 + kk * 32 + lk4 * 8) * 2) ^ (((d >> 3) & 7) << 4));
        bb[jd] = *(const short8*)((const char*)Vt + byte);
      }
      #pragma unroll
      for (int i = 0; i < 3; i++)
        #pragma unroll
        for (int jd = 0; jd < 4; jd++)
          o[i][jd] = __builtin_amdgcn_mfma_f32_16x16x32_bf16(a[i], bb[jd], o[i][jd], 0, 0, 0);
    }
  }
  // ---- r3 verbatim: store ----
  unsigned short* ob = aout + (size_t)bv * 192 * 512 + h * 64;
  #pragma unroll
  for (int i = 0; i < 3; i++)
    #pragma unroll
    for (int jd = 0; jd < 4; jd++)
      #pragma unroll
      for (int r = 0; r < 4; r++) {
        int t = w * 48 + i * 16 + lk4 * 4 + r;
        int d = jd * 16 + lr;
        ob[(size_t)t * 512 + d] = f2bf(o[i][jd][r]);
      }
}

extern "C" void kernel_launch(void* const* d_in, const int* in_sizes, int n_in,
                              void* d_out, int out_size, void* d_ws, size_t ws_size,
                              hipStream_t stream) {
  const float* x     = (const float*)d_in[0];
  const int*   obs   = (const int*)d_in[1];
  const int*   pad   = (const int*)d_in[2];
  const float* gamma = (const float*)d_in[3];
  const float* beta  = (const float*)d_in[4];
  const float* Wq    = (const float*)d_in[5];
  const float* Wp    = (const float*)d_in[6];
  const float* bp    = (const float*)d_in[7];
  float* out = (float*)d_out;
  char* ws = (char*)d_ws;

  const size_t M = 49152;  // BV * T1 = 256 * 192
  unsigned short* xn  = (unsigned short*)ws;                             // M*512 bf16 (reused as attn out)
  unsigned short* qkv = (unsigned short*)(ws + M * 512 * 2);             // M*1536 bf16
  unsigned short* Wtq = (unsigned short*)(ws + M * 512 * 2 + M * 1536 * 2);
  unsigned short* Wtp = Wtq + 1536 * 512;

  wprep<<<dim3(512), dim3(256), 0, stream>>>(Wq, Wp, Wtq, Wtp);
  ln_kernel<<<dim3(12288), dim3(256), 0, stream>>>(x, gamma, beta, xn);
  gemm_bt<0><<<dim3(12, 384), dim3(256), 0, stream>>>(
      xn, Wtq, qkv, nullptr, nullptr, nullptr, 49152, 1536, 512, 12);
  attn_kernel<<<dim3(8, 256), dim3(256), 0, stream>>>(qkv, xn, obs, pad);
  gemm_bt<1><<<dim3(4, 384), dim3(256), 0, stream>>>(
      xn, Wtp, nullptr, out, bp, x, 49152, 512, 512, 4);
}